// Round 11
// baseline (3673.403 us; speedup 1.0000x reference)
//
#include <hip/hip_runtime.h>
#include <hip/hip_bf16.h>
#include <math.h>

#define SEQ   1024
#define BATCH 256
#define IND   256
#define HID   256
#define NGATE 4

// ws layout:
//   wb    : bf16 [2 parts][4 gates][256 j][256 k], swizzled rows (1 MiB) @ 0
//   hr    : agent ring [2 slots][16 g][16 J][16 b][16 j] (256 KiB) @ 1 MiB
//   hfast : L2 mailbox mirror of hr (256 KiB)               @ 1.25 MiB
// each 8B word's element-0 LSB is the step stamp; single writer per region
#define WB_BYTES   (2 * NGATE * HID * 256 * 2)
#define HR_BYTES   (2 * 16 * 16 * 512)
#define REG_BYTES  512

typedef float        f32x4  __attribute__((ext_vector_type(4)));
typedef short        bf16x8 __attribute__((ext_vector_type(8)));
typedef unsigned int u32x4  __attribute__((ext_vector_type(4)));
typedef unsigned long long u64;

__device__ __forceinline__ short f2bf(float x) {
    __hip_bfloat16 h = __float2bfloat16(x);
    return *reinterpret_cast<short*>(&h);
}

__device__ __forceinline__ bf16x8 pack8(const float4& a, const float4& b) {
    union { short sh[8]; bf16x8 v; } u;
    u.sh[0] = f2bf(a.x); u.sh[1] = f2bf(a.y); u.sh[2] = f2bf(a.z); u.sh[3] = f2bf(a.w);
    u.sh[4] = f2bf(b.x); u.sh[5] = f2bf(b.y); u.sh[6] = f2bf(b.z); u.sh[7] = f2bf(b.w);
    return u.v;
}

__device__ __forceinline__ void gload_lds16(const void* g, void* l) {
    __builtin_amdgcn_global_load_lds(
        (const __attribute__((address_space(1))) unsigned int*)g,
        (__attribute__((address_space(3))) unsigned int*)l, 16, 0, 0);
}

__device__ __forceinline__ float sigmoid_f(float z) {
    return 1.f / (1.f + __expf(-z));
}
__device__ __forceinline__ float tanh_f(float v) {
    return 2.f / (1.f + __expf(-2.f * v)) - 1.f;
}

__device__ __forceinline__ bool stamp_ok(u64 q0, u64 q1, u64 ee) {
    return ((((q0 ^ ee) | (q1 ^ ee)) & 1ULL) == 0ULL);
}

// L1-bypassing 16B load served by the (XCD-shared) L2. Issue only; caller
// must s_waitcnt vmcnt(0) + sched_barrier(0) before reading the result.
__device__ __forceinline__ u32x4 load16_sc0(const void* p) {
    u32x4 v;
    asm volatile("global_load_dwordx4 %0, %1, off sc0" : "=v"(v) : "v"(p));
    return v;
}

// ---------------- prep kernels ----------------

__global__ __launch_bounds__(256) void prep_w(
    const float* __restrict__ Wf, const float* __restrict__ Wi,
    const float* __restrict__ Wg, const float* __restrict__ Wo,
    unsigned char* __restrict__ wb)
{
    int chunk = blockIdx.x * 256 + threadIdx.x;   // 65536 chunks of 8 floats
    int g  = chunk >> 14;
    int jj = (chunk >> 6) & 255;
    int k0 = (chunk & 63) * 8;
    int p  = k0 >> 8;
    int kk = k0 & 255;
    const float* W = (g == 0) ? Wf : (g == 1) ? Wi : (g == 2) ? Wg : Wo;
    const float* src = W + (size_t)jj * 512 + k0;
    float4 a = *reinterpret_cast<const float4*>(src);
    float4 b = *reinterpret_cast<const float4*>(src + 4);
    size_t dstrow = (size_t)((p * 4 + g) * 256 + jj);
    *reinterpret_cast<bf16x8*>(
        wb + dstrow * 512 + ((kk * 2) ^ ((jj & 7) << 4))) = pack8(a, b);
}

// Seed hr AND hfast, both slots, stamp bit 1 everywhere (slot0 = h0 payload,
// accepted at s=0; slot1 dummy, rejected until t=0 writes it). Poison 0xAA has
// LSB 0 and can never be accepted at odd-expectation steps thanks to seeding.
__global__ __launch_bounds__(256) void prep_h0(
    const float* __restrict__ h0, unsigned char* __restrict__ hr,
    unsigned char* __restrict__ hfast)
{
    int idx  = blockIdx.x * 256 + threadIdx.x;    // 32768 chunks of 8 B
    int slot = idx >> 14;
    int g    = (idx >> 10) & 15;
    int J    = (idx >> 6) & 15;
    int c    = idx & 63;
    int br   = c >> 2;
    int j4   = (c & 3) * 4;
    const float* src = h0 + (size_t)(g * 16 + br) * HID + J * 16 + j4;
    unsigned short v[4];
    #pragma unroll
    for (int i = 0; i < 4; ++i)
        v[i] = (unsigned short)((unsigned short)f2bf(src[i]) | 1u);
    u64 q = (u64)v[0] | ((u64)v[1] << 16) | ((u64)v[2] << 32) | ((u64)v[3] << 48);
    size_t off = (size_t)((slot * 16 + g) * 16 + J) * REG_BYTES + c * 8;
    *reinterpret_cast<u64*>(hr + off)    = q;
    *reinterpret_cast<u64*>(hfast + off) = q;
}

// ---------------- persistent sequence kernel ----------------
// 256 blocks x 64 threads (R9 structure). g_ = blk&15 -> the 16 peers of a
// group all share blk%8, i.e. one XCD under round-robin (heuristic only).
// Handoff: producer stores stamped words to hfast (plain -> local L2) AND hr
// (agent -> IF). Consumer: initial agent loads hidden under phase A; retry
// loop probes hfast via sc0 L2 loads with every-8th-round agent fallback on
// hr -> progress guaranteed regardless of XCD placement.
__global__ __launch_bounds__(64, 1) void lstm_seq(
    const float* __restrict__ x,  const float* __restrict__ c0,
    const float* __restrict__ bf_, const float* __restrict__ bi_,
    const float* __restrict__ bg_, const float* __restrict__ bo_,
    const unsigned char* __restrict__ wb, unsigned char* __restrict__ hr,
    unsigned char* __restrict__ hfast,
    float* __restrict__ out, float* __restrict__ hx, float* __restrict__ cxg)
{
    extern __shared__ __align__(16) unsigned char smem[];   // 64 KiB

    const int lane = threadIdx.x & 63;
    const int blk  = blockIdx.x;
    const int g_   = blk & 15;          // batch group (XCD-local peers)
    const int J    = blk >> 4;          // j-tile 0..15
    const int j0   = J * 16;
    const int b0   = g_ * 16;

    const int lrow = lane & 15;
    const int hi   = lane >> 4;
    const int j    = j0 + lrow;

    // ---- stage W tile (64 KiB) into LDS once
    #pragma unroll
    for (int i = 0; i < 64; ++i) {
        gload_lds16(wb + ((size_t)((i >> 3) * 256 + j0 + (i & 7) * 2)) * 512
                       + lane * 16,
                    smem + i * 1024);
    }
    const float biasF = bf_[j], biasI = bi_[j], biasG = bg_[j], biasO = bo_[j];
    float cst[4];
    #pragma unroll
    for (int r = 0; r < 4; ++r)
        cst[r] = c0[(b0 + hi * 4 + r) * HID + j];
    __syncthreads();    // drains gload_lds

    // ---- read all W fragments into the register file: wf[part][kc][gate]
    const int bswz = (lrow & 7) << 4;
    bf16x8 wf[2][8][4];
    #pragma unroll
    for (int p = 0; p < 2; ++p) {
        #pragma unroll
        for (int kc = 0; kc < 8; ++kc) {
            int wbyte = (kc * 64 + hi * 16) ^ bswz;
            #pragma unroll
            for (int gg = 0; gg < 4; ++gg)
                wf[p][kc][gg] = *reinterpret_cast<const bf16x8*>(
                    smem + p * 32768 + gg * 8192 + lrow * 512 + wbyte);
        }
    }
    // steady-state LDS: h stage [64 x 8B] @0, out stage [64 x 16B] @512

    // ---- x pipeline: xpk = packed x(s); xt = in-flight x(s+1)
    float4 xt0[8], xt1[8];
    bf16x8 xpk[8];
    {
        const float* xr = x + (size_t)(b0 + lrow) * IND;
        #pragma unroll
        for (int kc = 0; kc < 8; ++kc) {
            const float* p = xr + kc * 32 + hi * 8;
            xt0[kc] = *reinterpret_cast<const float4*>(p);
            xt1[kc] = *reinterpret_cast<const float4*>(p + 4);
        }
        #pragma unroll
        for (int kc = 0; kc < 8; ++kc) xpk[kc] = pack8(xt0[kc], xt1[kc]);
        const float* xr1 = x + ((size_t)BATCH + b0 + lrow) * IND;
        #pragma unroll
        for (int kc = 0; kc < 8; ++kc) {
            const float* p = xr1 + kc * 32 + hi * 8;
            xt0[kc] = *reinterpret_cast<const float4*>(p);
            xt1[kc] = *reinterpret_cast<const float4*>(p + 4);
        }
    }

    unsigned char* regc[2] = {
        hr + (size_t)((0 * 16 + g_) * 16) * REG_BYTES,
        hr + (size_t)((1 * 16 + g_) * 16) * REG_BYTES };
    unsigned char* fstc[2] = {
        hfast + (size_t)((0 * 16 + g_) * 16) * REG_BYTES,
        hfast + (size_t)((1 * 16 + g_) * 16) * REG_BYTES };
    unsigned char* regp[2] = { regc[0] + J * REG_BYTES, regc[1] + J * REG_BYTES };
    unsigned char* fstp[2] = { fstc[0] + J * REG_BYTES, fstc[1] + J * REG_BYTES };

    for (int s = 0; s < SEQ; ++s) {
        const u64 ee = (u64)(((unsigned)(s + 3) >> 1) & 1);   // expected stamp bit
        const unsigned char* hsrc = regc[s & 1];
        const unsigned char* fsrc = fstc[s & 1];
        const int uoff = lrow * 32 + (hi & 1) * 16;           // within-region

        // ---- issue initial h(s-1) agent loads (latency hides under phase A)
        u64 hq0[8], hq1[8];
        #pragma unroll
        for (int kc = 0; kc < 8; ++kc) {
            const u64* p = reinterpret_cast<const u64*>(
                hsrc + (2 * kc + (hi >> 1)) * REG_BYTES + uoff);
            hq0[kc] = __hip_atomic_load(p,     __ATOMIC_RELAXED, __HIP_MEMORY_SCOPE_AGENT);
            hq1[kc] = __hip_atomic_load(p + 1, __ATOMIC_RELAXED, __HIP_MEMORY_SCOPE_AGENT);
        }
        __builtin_amdgcn_sched_barrier(0);

        // ---- phase A: x-part MFMA (pure register work)
        f32x4 aF = {0.f, 0.f, 0.f, 0.f};
        f32x4 aI = {0.f, 0.f, 0.f, 0.f};
        f32x4 aG = {0.f, 0.f, 0.f, 0.f};
        f32x4 aO = {0.f, 0.f, 0.f, 0.f};
        #pragma unroll
        for (int kc = 0; kc < 8; ++kc) {
            aF = __builtin_amdgcn_mfma_f32_16x16x32_bf16(xpk[kc], wf[0][kc][0], aF, 0, 0, 0);
            aI = __builtin_amdgcn_mfma_f32_16x16x32_bf16(xpk[kc], wf[0][kc][1], aI, 0, 0, 0);
            aG = __builtin_amdgcn_mfma_f32_16x16x32_bf16(xpk[kc], wf[0][kc][2], aG, 0, 0, 0);
            aO = __builtin_amdgcn_mfma_f32_16x16x32_bf16(xpk[kc], wf[0][kc][3], aO, 0, 0, 0);
        }
        // pack x(s+1) (VALU only; its loads landed a full step ago)
        #pragma unroll
        for (int kc = 0; kc < 8; ++kc) xpk[kc] = pack8(xt0[kc], xt1[kc]);
        __builtin_amdgcn_sched_barrier(0);

        // ---- wait kc 0-3 -> MFMA; then kc 4-7 -> MFMA
        #pragma unroll
        for (int half = 0; half < 2; ++half) {
            const int kb = half * 4;
            unsigned pend = 0;
            #pragma unroll
            for (int kc = 0; kc < 4; ++kc)
                if (!stamp_ok(hq0[kb + kc], hq1[kb + kc], ee)) pend |= (1u << kc);
            int round = 0;
            while (pend) {
                if ((round & 7) == 7) {
                    // agent fallback (progress even if XCD heuristic breaks)
                    #pragma unroll
                    for (int kc = 0; kc < 4; ++kc) {
                        if (pend & (1u << kc)) {
                            const u64* p = reinterpret_cast<const u64*>(
                                hsrc + (2 * (kb + kc) + (hi >> 1)) * REG_BYTES + uoff);
                            hq0[kb + kc] = __hip_atomic_load(p,     __ATOMIC_RELAXED, __HIP_MEMORY_SCOPE_AGENT);
                            hq1[kb + kc] = __hip_atomic_load(p + 1, __ATOMIC_RELAXED, __HIP_MEMORY_SCOPE_AGENT);
                        }
                    }
                } else {
                    // fast path: L2-served sc0 probes of the mailbox
                    u32x4 pv[4];
                    #pragma unroll
                    for (int kc = 0; kc < 4; ++kc)
                        if (pend & (1u << kc))
                            pv[kc] = load16_sc0(
                                fsrc + (2 * (kb + kc) + (hi >> 1)) * REG_BYTES + uoff);
                    asm volatile("s_waitcnt vmcnt(0)" ::: "memory");
                    __builtin_amdgcn_sched_barrier(0);
                    #pragma unroll
                    for (int kc = 0; kc < 4; ++kc) {
                        if (pend & (1u << kc)) {
                            hq0[kb + kc] = (u64)pv[kc].x | ((u64)pv[kc].y << 32);
                            hq1[kb + kc] = (u64)pv[kc].z | ((u64)pv[kc].w << 32);
                        }
                    }
                }
                #pragma unroll
                for (int kc = 0; kc < 4; ++kc)
                    if ((pend & (1u << kc)) &&
                        stamp_ok(hq0[kb + kc], hq1[kb + kc], ee)) pend &= ~(1u << kc);
                ++round;
            }
            #pragma unroll
            for (int kc = 0; kc < 4; ++kc) {
                union { u64 q[2]; bf16x8 v; } u;
                u.q[0] = hq0[kb + kc]; u.q[1] = hq1[kb + kc];
                aF = __builtin_amdgcn_mfma_f32_16x16x32_bf16(u.v, wf[1][kb + kc][0], aF, 0, 0, 0);
                aI = __builtin_amdgcn_mfma_f32_16x16x32_bf16(u.v, wf[1][kb + kc][1], aI, 0, 0, 0);
                aG = __builtin_amdgcn_mfma_f32_16x16x32_bf16(u.v, wf[1][kb + kc][2], aG, 0, 0, 0);
                aO = __builtin_amdgcn_mfma_f32_16x16x32_bf16(u.v, wf[1][kb + kc][3], aO, 0, 0, 0);
            }
        }

        // ---- issue x(s+2) now (after the retry loop, so vmcnt(0) probes
        //      never wait on these HBM loads; consumed 1.5 steps later)
        if (s + 2 < SEQ) {
            const float* xr = x + ((size_t)(s + 2) * BATCH + b0 + lrow) * IND;
            #pragma unroll
            for (int kc = 0; kc < 8; ++kc) {
                const float* p = xr + kc * 32 + hi * 8;
                xt0[kc] = *reinterpret_cast<const float4*>(p);
                xt1[kc] = *reinterpret_cast<const float4*>(p + 4);
            }
        }

        // ---- epilogue: gates + c update
        float hv[4];
        #pragma unroll
        for (int r = 0; r < 4; ++r) {
            float fg = sigmoid_f(aF[r] + biasF);
            float ig = sigmoid_f(aI[r] + biasI);
            float gg = tanh_f(aG[r] + biasG);
            float og = sigmoid_f(aO[r] + biasO);
            cst[r] = fg * cst[r] + ig * gg;
            hv[r]  = og * tanh_f(cst[r]);
        }
        #pragma unroll
        for (int r = 0; r < 4; ++r) {
            int bl = hi * 4 + r;
            *reinterpret_cast<short*>(smem + bl * 32 + lrow * 2) = f2bf(hv[r]);
            *reinterpret_cast<float*>(smem + 512 + bl * 64 + lrow * 4) = hv[r];
        }
        __builtin_amdgcn_sched_barrier(0);
        asm volatile("s_waitcnt lgkmcnt(0)" ::: "memory");
        __builtin_amdgcn_sched_barrier(0);

        // ---- stamped 8B stores: fast mailbox first (L2), then agent ring
        {
            u64 wv = *reinterpret_cast<const u64*>(smem + lane * 8);
            wv = (wv & ~1ULL) | (u64)((s >> 1) & 1);
            *reinterpret_cast<volatile u64*>(fstp[(s + 1) & 1] + lane * 8) = wv;
            __hip_atomic_store(
                reinterpret_cast<u64*>(regp[(s + 1) & 1] + lane * 8),
                wv, __ATOMIC_RELAXED, __HIP_MEMORY_SCOPE_AGENT);
        }
        {
            float4 ov = *reinterpret_cast<const float4*>(smem + 512 + lane * 16);
            *reinterpret_cast<float4*>(
                out + (size_t)s * (BATCH * HID)
                    + (size_t)(b0 + (lane >> 2)) * HID + j0 + (lane & 3) * 4) = ov;
        }
        if (s == SEQ - 1) {
            #pragma unroll
            for (int r = 0; r < 4; ++r) {
                int gi = (b0 + hi * 4 + r) * HID + j;
                hx[gi] = hv[r]; cxg[gi] = cst[r];
            }
        }
    }
}

extern "C" void kernel_launch(void* const* d_in, const int* in_sizes, int n_in,
                              void* d_out, int out_size, void* d_ws, size_t ws_size,
                              hipStream_t stream) {
    const float* x  = (const float*)d_in[0];
    const float* h0 = (const float*)d_in[1];
    const float* c0 = (const float*)d_in[2];
    const float* Wf = (const float*)d_in[3];
    const float* bf = (const float*)d_in[4];
    const float* Wi = (const float*)d_in[5];
    const float* bi = (const float*)d_in[6];
    const float* Wg = (const float*)d_in[7];
    const float* bg = (const float*)d_in[8];
    const float* Wo = (const float*)d_in[9];
    const float* bo = (const float*)d_in[10];

    float* out = (float*)d_out;
    float* hx  = out + (size_t)SEQ * BATCH * HID;
    float* cx  = hx + BATCH * HID;

    unsigned char* wb = (unsigned char*)d_ws;
    unsigned char* hr = wb + WB_BYTES;
    unsigned char* hf = hr + HR_BYTES;

    prep_w<<<256, 256, 0, stream>>>(Wf, Wi, Wg, Wo, wb);
    prep_h0<<<128, 256, 0, stream>>>(h0, hr, hf);
    lstm_seq<<<256, 64, 65536, stream>>>(x, c0, bf, bi, bg, bo,
                                         wb, hr, hf, out, hx, cx);
}

// Round 12
// 2974.527 us; speedup vs baseline: 1.2350x; 1.2350x over previous
//
#include <hip/hip_runtime.h>
#include <hip/hip_bf16.h>
#include <math.h>

#define SEQ   1024
#define BATCH 256
#define IND   256
#define HID   256
#define NGATE 4

// ws layout:
//   wb : bf16 [2 parts][4 gates][256 j][256 k], swizzled rows (1 MiB) @ 0
//   hr : ring [2 slots][16 g][16 J] regions of 512B: word(b,j4) = 4 bf16
//        {h[b][16J+j4..+3]}, elem-0 LSB = step stamp; single writer @ 1 MiB
#define WB_BYTES   (2 * NGATE * HID * 256 * 2)
#define REG_BYTES  512

typedef float  f32x4  __attribute__((ext_vector_type(4)));
typedef short  bf16x8 __attribute__((ext_vector_type(8)));
typedef unsigned long long u64;

__device__ __forceinline__ short f2bf(float x) {
    __hip_bfloat16 h = __float2bfloat16(x);
    return *reinterpret_cast<short*>(&h);
}

__device__ __forceinline__ bf16x8 pack8(const float4& a, const float4& b) {
    union { short sh[8]; bf16x8 v; } u;
    u.sh[0] = f2bf(a.x); u.sh[1] = f2bf(a.y); u.sh[2] = f2bf(a.z); u.sh[3] = f2bf(a.w);
    u.sh[4] = f2bf(b.x); u.sh[5] = f2bf(b.y); u.sh[6] = f2bf(b.z); u.sh[7] = f2bf(b.w);
    return u.v;
}

__device__ __forceinline__ void gload_lds16(const void* g, void* l) {
    __builtin_amdgcn_global_load_lds(
        (const __attribute__((address_space(1))) unsigned int*)g,
        (__attribute__((address_space(3))) unsigned int*)l, 16, 0, 0);
}

__device__ __forceinline__ float sigmoid_f(float z) {
    return 1.f / (1.f + __expf(-z));
}
__device__ __forceinline__ float tanh_f(float v) {
    return 2.f / (1.f + __expf(-2.f * v)) - 1.f;
}

__device__ __forceinline__ bool stamp_ok(u64 q0, u64 q1, u64 ee) {
    return ((((q0 ^ ee) | (q1 ^ ee)) & 1ULL) == 0ULL);
}

// device-coherent 16B probe (two 8B single-copy-atomic loads); ISSUE ONLY —
// caller must s_waitcnt + sched_barrier(0) before reading q0/q1.
__device__ __forceinline__ void probe2(const void* p, u64& q0, u64& q1) {
    asm volatile("global_load_dwordx2 %0, %2, off sc0 sc1\n\t"
                 "global_load_dwordx2 %1, %2, off offset:8 sc0 sc1"
                 : "=&v"(q0), "=&v"(q1) : "v"(p));
}

// ---------------- prep kernels (identical to R9) ----------------

__global__ __launch_bounds__(256) void prep_w(
    const float* __restrict__ Wf, const float* __restrict__ Wi,
    const float* __restrict__ Wg, const float* __restrict__ Wo,
    unsigned char* __restrict__ wb)
{
    int chunk = blockIdx.x * 256 + threadIdx.x;   // 65536 chunks of 8 floats
    int g  = chunk >> 14;
    int jj = (chunk >> 6) & 255;
    int k0 = (chunk & 63) * 8;
    int p  = k0 >> 8;
    int kk = k0 & 255;
    const float* W = (g == 0) ? Wf : (g == 1) ? Wi : (g == 2) ? Wg : Wo;
    const float* src = W + (size_t)jj * 512 + k0;
    float4 a = *reinterpret_cast<const float4*>(src);
    float4 b = *reinterpret_cast<const float4*>(src + 4);
    size_t dstrow = (size_t)((p * 4 + g) * 256 + jj);
    *reinterpret_cast<bf16x8*>(
        wb + dstrow * 512 + ((kk * 2) ^ ((jj & 7) << 4))) = pack8(a, b);
}

__global__ __launch_bounds__(256) void prep_h0(
    const float* __restrict__ h0, unsigned char* __restrict__ hr)
{
    int idx  = blockIdx.x * 256 + threadIdx.x;    // 32768 chunks of 8 B
    int slot = idx >> 14;
    int g    = (idx >> 10) & 15;
    int J    = (idx >> 6) & 15;
    int c    = idx & 63;
    int br   = c >> 2;
    int j4   = (c & 3) * 4;
    const float* src = h0 + (size_t)(g * 16 + br) * HID + J * 16 + j4;
    unsigned short v[4];
    #pragma unroll
    for (int i = 0; i < 4; ++i)
        v[i] = (unsigned short)((unsigned short)f2bf(src[i]) | 1u);
    u64 q = (u64)v[0] | ((u64)v[1] << 16) | ((u64)v[2] << 32) | ((u64)v[3] << 48);
    *reinterpret_cast<u64*>(
        hr + (size_t)((slot * 16 + g) * 16 + J) * REG_BYTES + c * 8) = q;
}

// ---------------- persistent sequence kernel ----------------
// 256 blocks x 64 threads. g_ = blk&15 (XCD-local peers, heuristic),
// J = blk>>4. OPERAND-SWAPPED MFMA: acc col=b, row=j -> each lane's 4 acc
// values = 4 consecutive j at one b = ONE ring word; no LDS transpose.
// h-part W in registers (critical path); x-part W re-read from LDS in phase A
// (hidden under the handoff RT). Probing: 2-deep pipelined asm rounds with
// counted vmcnt(16).
__global__ __launch_bounds__(64, 1) void lstm_seq(
    const float* __restrict__ x,  const float* __restrict__ c0,
    const float* __restrict__ bf_, const float* __restrict__ bi_,
    const float* __restrict__ bg_, const float* __restrict__ bo_,
    const unsigned char* __restrict__ wb, unsigned char* __restrict__ hr,
    float* __restrict__ out, float* __restrict__ hx, float* __restrict__ cxg)
{
    extern __shared__ __align__(16) unsigned char smem[];   // 64 KiB

    const int lane = threadIdx.x & 63;
    const int blk  = blockIdx.x;
    const int g_   = blk & 15;
    const int J    = blk >> 4;
    const int j0   = J * 16;
    const int b0   = g_ * 16;

    const int lrow = lane & 15;
    const int hi   = lane >> 4;
    const int b    = b0 + lrow;          // this lane's batch row (C col)
    const int jv   = j0 + hi * 4;        // this lane's first j (C row base)

    // ---- stage W tile (64 KiB) into LDS once
    #pragma unroll
    for (int i = 0; i < 64; ++i) {
        gload_lds16(wb + ((size_t)((i >> 3) * 256 + j0 + (i & 7) * 2)) * 512
                       + lane * 16,
                    smem + i * 1024);
    }
    const float4 biasF4 = *reinterpret_cast<const float4*>(bf_ + jv);
    const float4 biasI4 = *reinterpret_cast<const float4*>(bi_ + jv);
    const float4 biasG4 = *reinterpret_cast<const float4*>(bg_ + jv);
    const float4 biasO4 = *reinterpret_cast<const float4*>(bo_ + jv);
    float4 cst = *reinterpret_cast<const float4*>(c0 + (size_t)b * HID + jv);
    __syncthreads();    // drains gload_lds

    // ---- h-part W fragments -> registers (128 VGPR): wfh[kc][gate]
    const int bswz = (lrow & 7) << 4;
    bf16x8 wfh[8][4];
    #pragma unroll
    for (int kc = 0; kc < 8; ++kc) {
        int wbyte = (kc * 64 + hi * 16) ^ bswz;
        #pragma unroll
        for (int gg = 0; gg < 4; ++gg)
            wfh[kc][gg] = *reinterpret_cast<const bf16x8*>(
                smem + 32768 + gg * 8192 + lrow * 512 + wbyte);
    }
    // x-part W stays in LDS (smem + gate*8192 + lrow*512), re-read each step.

    // ---- x pipeline: xpk = packed x(s); xt = in-flight x(s+1)
    float4 xt0[8], xt1[8];
    bf16x8 xpk[8];
    {
        const float* xr = x + (size_t)b * IND;
        #pragma unroll
        for (int kc = 0; kc < 8; ++kc) {
            const float* p = xr + kc * 32 + hi * 8;
            xt0[kc] = *reinterpret_cast<const float4*>(p);
            xt1[kc] = *reinterpret_cast<const float4*>(p + 4);
        }
        #pragma unroll
        for (int kc = 0; kc < 8; ++kc) xpk[kc] = pack8(xt0[kc], xt1[kc]);
        const float* xr1 = x + ((size_t)BATCH + b) * IND;
        #pragma unroll
        for (int kc = 0; kc < 8; ++kc) {
            const float* p = xr1 + kc * 32 + hi * 8;
            xt0[kc] = *reinterpret_cast<const float4*>(p);
            xt1[kc] = *reinterpret_cast<const float4*>(p + 4);
        }
    }

    unsigned char* regc[2] = {
        hr + (size_t)((0 * 16 + g_) * 16) * REG_BYTES,
        hr + (size_t)((1 * 16 + g_) * 16) * REG_BYTES };
    unsigned char* regp[2] = { regc[0] + J * REG_BYTES, regc[1] + J * REG_BYTES };
    const int uoff = lrow * 32 + (hi & 1) * 16;   // consumer in-region offset

    for (int s = 0; s < SEQ; ++s) {
        const u64 ee = (u64)(((unsigned)(s + 3) >> 1) & 1);
        const unsigned char* hsrc = regc[s & 1];

        // ---- initial probe round (qa), latency hides under phase A
        u64 qa0[8], qa1[8], qb0[8], qb1[8];
        #pragma unroll
        for (int kc = 0; kc < 8; ++kc)
            probe2(hsrc + (2 * kc + (hi >> 1)) * REG_BYTES + uoff,
                   qa0[kc], qa1[kc]);
        __builtin_amdgcn_sched_barrier(0);

        // ---- phase A: x-part MFMA, W from LDS (off the critical chain)
        f32x4 aF = {0.f, 0.f, 0.f, 0.f};
        f32x4 aI = {0.f, 0.f, 0.f, 0.f};
        f32x4 aG = {0.f, 0.f, 0.f, 0.f};
        f32x4 aO = {0.f, 0.f, 0.f, 0.f};
        #pragma unroll
        for (int kc = 0; kc < 8; ++kc) {
            int wbyte = (kc * 64 + hi * 16) ^ bswz;
            const unsigned char* wr = smem + lrow * 512 + wbyte;
            bf16x8 vF = *reinterpret_cast<const bf16x8*>(wr);
            bf16x8 vI = *reinterpret_cast<const bf16x8*>(wr + 8192);
            bf16x8 vG = *reinterpret_cast<const bf16x8*>(wr + 16384);
            bf16x8 vO = *reinterpret_cast<const bf16x8*>(wr + 24576);
            aF = __builtin_amdgcn_mfma_f32_16x16x32_bf16(vF, xpk[kc], aF, 0, 0, 0);
            aI = __builtin_amdgcn_mfma_f32_16x16x32_bf16(vI, xpk[kc], aI, 0, 0, 0);
            aG = __builtin_amdgcn_mfma_f32_16x16x32_bf16(vG, xpk[kc], aG, 0, 0, 0);
            aO = __builtin_amdgcn_mfma_f32_16x16x32_bf16(vO, xpk[kc], aO, 0, 0, 0);
        }
        // pack x(s+1) (loads landed a full step ago)
        #pragma unroll
        for (int kc = 0; kc < 8; ++kc) xpk[kc] = pack8(xt0[kc], xt1[kc]);
        __builtin_amdgcn_sched_barrier(0);

        // ---- 2-deep pipelined stamp-wait: issue qb, wait qa (vmcnt(16)),
        //      check, copy. Round cadence ~ RT/2.
        unsigned pend = 0xffu;
        while (pend) {
            #pragma unroll
            for (int kc = 0; kc < 8; ++kc)
                probe2(hsrc + (2 * kc + (hi >> 1)) * REG_BYTES + uoff,
                       qb0[kc], qb1[kc]);
            asm volatile("s_waitcnt vmcnt(16)" ::: "memory");
            __builtin_amdgcn_sched_barrier(0);
            #pragma unroll
            for (int kc = 0; kc < 8; ++kc)
                if ((pend & (1u << kc)) && stamp_ok(qa0[kc], qa1[kc], ee))
                    pend &= ~(1u << kc);
            if (pend) {
                #pragma unroll
                for (int kc = 0; kc < 8; ++kc) { qa0[kc] = qb0[kc]; qa1[kc] = qb1[kc]; }
            }
        }
        __builtin_amdgcn_sched_barrier(0);

        // ---- phase B: h-part MFMA from accepted qa + register W
        #pragma unroll
        for (int kc = 0; kc < 8; ++kc) {
            union { u64 q[2]; bf16x8 v; } u;
            u.q[0] = qa0[kc]; u.q[1] = qa1[kc];
            aF = __builtin_amdgcn_mfma_f32_16x16x32_bf16(wfh[kc][0], u.v, aF, 0, 0, 0);
            aI = __builtin_amdgcn_mfma_f32_16x16x32_bf16(wfh[kc][1], u.v, aI, 0, 0, 0);
            aG = __builtin_amdgcn_mfma_f32_16x16x32_bf16(wfh[kc][2], u.v, aG, 0, 0, 0);
            aO = __builtin_amdgcn_mfma_f32_16x16x32_bf16(wfh[kc][3], u.v, aO, 0, 0, 0);
        }

        // ---- epilogue: 4 consecutive j at this lane's b — all register-local
        float hv[4];
        #pragma unroll
        for (int r = 0; r < 4; ++r) {
            float fg = sigmoid_f(aF[r] + ((const float*)&biasF4)[r]);
            float ig = sigmoid_f(aI[r] + ((const float*)&biasI4)[r]);
            float gg = tanh_f(aG[r] + ((const float*)&biasG4)[r]);
            float og = sigmoid_f(aO[r] + ((const float*)&biasO4)[r]);
            ((float*)&cst)[r] = fg * ((const float*)&cst)[r] + ig * gg;
            hv[r] = og * tanh_f(((const float*)&cst)[r]);
        }

        // ---- stamped 8B ring word straight from registers (no transpose)
        {
            u64 wv = (u64)(unsigned short)f2bf(hv[0])
                   | ((u64)(unsigned short)f2bf(hv[1]) << 16)
                   | ((u64)(unsigned short)f2bf(hv[2]) << 32)
                   | ((u64)(unsigned short)f2bf(hv[3]) << 48);
            wv = (wv & ~1ULL) | (u64)((s >> 1) & 1);
            __hip_atomic_store(
                reinterpret_cast<u64*>(regp[(s + 1) & 1] + lrow * 32 + hi * 8),
                wv, __ATOMIC_RELAXED, __HIP_MEMORY_SCOPE_AGENT);
        }
        // ---- out store: float4 of 4 consecutive j (off-chain)
        {
            float4 ov = { hv[0], hv[1], hv[2], hv[3] };
            *reinterpret_cast<float4*>(
                out + (size_t)s * (BATCH * HID) + (size_t)b * HID + jv) = ov;
        }
        // ---- x(s+2) prefetch (after stores; consumed 1.5 steps later)
        if (s + 2 < SEQ) {
            const float* xr = x + ((size_t)(s + 2) * BATCH + b) * IND;
            #pragma unroll
            for (int kc = 0; kc < 8; ++kc) {
                const float* p = xr + kc * 32 + hi * 8;
                xt0[kc] = *reinterpret_cast<const float4*>(p);
                xt1[kc] = *reinterpret_cast<const float4*>(p + 4);
            }
        }
        if (s == SEQ - 1) {
            *reinterpret_cast<float4*>(hx  + (size_t)b * HID + jv) =
                (float4){ hv[0], hv[1], hv[2], hv[3] };
            *reinterpret_cast<float4*>(cxg + (size_t)b * HID + jv) = cst;
        }
        // keep qb registers alive until iteration end: dangling pipelined
        // probe loads may still land in them (WAR hazard guard)
        asm volatile("" ::
            "v"(qb0[0]), "v"(qb0[1]), "v"(qb0[2]), "v"(qb0[3]),
            "v"(qb0[4]), "v"(qb0[5]), "v"(qb0[6]), "v"(qb0[7]),
            "v"(qb1[0]), "v"(qb1[1]), "v"(qb1[2]), "v"(qb1[3]),
            "v"(qb1[4]), "v"(qb1[5]), "v"(qb1[6]), "v"(qb1[7]));
    }
}

extern "C" void kernel_launch(void* const* d_in, const int* in_sizes, int n_in,
                              void* d_out, int out_size, void* d_ws, size_t ws_size,
                              hipStream_t stream) {
    const float* x  = (const float*)d_in[0];
    const float* h0 = (const float*)d_in[1];
    const float* c0 = (const float*)d_in[2];
    const float* Wf = (const float*)d_in[3];
    const float* bf = (const float*)d_in[4];
    const float* Wi = (const float*)d_in[5];
    const float* bi = (const float*)d_in[6];
    const float* Wg = (const float*)d_in[7];
    const float* bg = (const float*)d_in[8];
    const float* Wo = (const float*)d_in[9];
    const float* bo = (const float*)d_in[10];

    float* out = (float*)d_out;
    float* hx  = out + (size_t)SEQ * BATCH * HID;
    float* cx  = hx + BATCH * HID;

    unsigned char* wb = (unsigned char*)d_ws;
    unsigned char* hr = wb + WB_BYTES;

    prep_w<<<256, 256, 0, stream>>>(Wf, Wi, Wg, Wo, wb);
    prep_h0<<<128, 256, 0, stream>>>(h0, hr);
    lstm_seq<<<256, 64, 65536, stream>>>(x, c0, bf, bi, bg, bo,
                                         wb, hr, out, hx, cx);
}

// Round 13
// 2721.420 us; speedup vs baseline: 1.3498x; 1.0930x over previous
//
#include <hip/hip_runtime.h>
#include <hip/hip_bf16.h>
#include <math.h>

#define SEQ   1024
#define BATCH 256
#define IND   256
#define HID   256
#define NGATE 4

// ws layout:
//   wb : bf16 [2 parts][4 gates][256 j][256 k], swizzled rows (1 MiB) @ 0
//   hr : ring [2 slots][16 g][16 J] regions of 512B: word(b,j4) = 4 bf16
//        {h[b][16J+j4..+3]}, elem-0 LSB = step stamp; single writer @ 1 MiB
#define WB_BYTES   (2 * NGATE * HID * 256 * 2)
#define REG_BYTES  512

typedef float  f32x4  __attribute__((ext_vector_type(4)));
typedef short  bf16x8 __attribute__((ext_vector_type(8)));
typedef unsigned long long u64;

__device__ __forceinline__ short f2bf(float x) {
    __hip_bfloat16 h = __float2bfloat16(x);
    return *reinterpret_cast<short*>(&h);
}

__device__ __forceinline__ bf16x8 pack8(const float4& a, const float4& b) {
    union { short sh[8]; bf16x8 v; } u;
    u.sh[0] = f2bf(a.x); u.sh[1] = f2bf(a.y); u.sh[2] = f2bf(a.z); u.sh[3] = f2bf(a.w);
    u.sh[4] = f2bf(b.x); u.sh[5] = f2bf(b.y); u.sh[6] = f2bf(b.z); u.sh[7] = f2bf(b.w);
    return u.v;
}

__device__ __forceinline__ void gload_lds16(const void* g, void* l) {
    __builtin_amdgcn_global_load_lds(
        (const __attribute__((address_space(1))) unsigned int*)g,
        (__attribute__((address_space(3))) unsigned int*)l, 16, 0, 0);
}

__device__ __forceinline__ float sigmoid_f(float z) {
    return 1.f / (1.f + __expf(-z));
}
__device__ __forceinline__ float tanh_f(float v) {
    return 2.f / (1.f + __expf(-2.f * v)) - 1.f;
}

__device__ __forceinline__ bool stamp_ok(u64 q0, u64 q1, u64 ee) {
    return ((((q0 ^ ee) | (q1 ^ ee)) & 1ULL) == 0ULL);
}

// ---------------- prep kernels (identical to R9/R12) ----------------

__global__ __launch_bounds__(256) void prep_w(
    const float* __restrict__ Wf, const float* __restrict__ Wi,
    const float* __restrict__ Wg, const float* __restrict__ Wo,
    unsigned char* __restrict__ wb)
{
    int chunk = blockIdx.x * 256 + threadIdx.x;   // 65536 chunks of 8 floats
    int g  = chunk >> 14;
    int jj = (chunk >> 6) & 255;
    int k0 = (chunk & 63) * 8;
    int p  = k0 >> 8;
    int kk = k0 & 255;
    const float* W = (g == 0) ? Wf : (g == 1) ? Wi : (g == 2) ? Wg : Wo;
    const float* src = W + (size_t)jj * 512 + k0;
    float4 a = *reinterpret_cast<const float4*>(src);
    float4 b = *reinterpret_cast<const float4*>(src + 4);
    size_t dstrow = (size_t)((p * 4 + g) * 256 + jj);
    *reinterpret_cast<bf16x8*>(
        wb + dstrow * 512 + ((kk * 2) ^ ((jj & 7) << 4))) = pack8(a, b);
}

__global__ __launch_bounds__(256) void prep_h0(
    const float* __restrict__ h0, unsigned char* __restrict__ hr)
{
    int idx  = blockIdx.x * 256 + threadIdx.x;    // 32768 chunks of 8 B
    int slot = idx >> 14;
    int g    = (idx >> 10) & 15;
    int J    = (idx >> 6) & 15;
    int c    = idx & 63;
    int br   = c >> 2;
    int j4   = (c & 3) * 4;
    const float* src = h0 + (size_t)(g * 16 + br) * HID + J * 16 + j4;
    unsigned short v[4];
    #pragma unroll
    for (int i = 0; i < 4; ++i)
        v[i] = (unsigned short)((unsigned short)f2bf(src[i]) | 1u);
    u64 q = (u64)v[0] | ((u64)v[1] << 16) | ((u64)v[2] << 32) | ((u64)v[3] << 48);
    *reinterpret_cast<u64*>(
        hr + (size_t)((slot * 16 + g) * 16 + J) * REG_BYTES + c * 8) = q;
}

// ---------------- persistent sequence kernel ----------------
// 256 blocks x 64 threads. g_ = blk&15 (XCD-local peers, heuristic),
// J = blk>>4. Operand-swapped MFMA (acc col=b, row=j): each lane owns
// (b = b0+lrow, j = j0+hi*4 .. +3) -> stamped 8B ring word packed straight
// from registers, no LDS transpose. BOTH W parts live in registers; LDS is
// used only for the one-time W staging. Probe loop = R9's compiler-atomic
// half-split (kc 0-3 consumed while 4-7 settle). x(s+2) prefetch issued
// AFTER the chain so retry vmcnt drains never wait on HBM.
__global__ __launch_bounds__(64, 1) void lstm_seq(
    const float* __restrict__ x,  const float* __restrict__ c0,
    const float* __restrict__ bf_, const float* __restrict__ bi_,
    const float* __restrict__ bg_, const float* __restrict__ bo_,
    const unsigned char* __restrict__ wb, unsigned char* __restrict__ hr,
    float* __restrict__ out, float* __restrict__ hx, float* __restrict__ cxg)
{
    extern __shared__ __align__(16) unsigned char smem[];   // 64 KiB, init only

    const int lane = threadIdx.x & 63;
    const int blk  = blockIdx.x;
    const int g_   = blk & 15;
    const int J    = blk >> 4;
    const int j0   = J * 16;
    const int b0   = g_ * 16;

    const int lrow = lane & 15;
    const int hi   = lane >> 4;
    const int b    = b0 + lrow;          // this lane's batch row (acc col)
    const int jv   = j0 + hi * 4;        // this lane's first j (acc row base)

    // ---- stage W tile (64 KiB) into LDS once
    #pragma unroll
    for (int i = 0; i < 64; ++i) {
        gload_lds16(wb + ((size_t)((i >> 3) * 256 + j0 + (i & 7) * 2)) * 512
                       + lane * 16,
                    smem + i * 1024);
    }
    const float4 biasF4 = *reinterpret_cast<const float4*>(bf_ + jv);
    const float4 biasI4 = *reinterpret_cast<const float4*>(bi_ + jv);
    const float4 biasG4 = *reinterpret_cast<const float4*>(bg_ + jv);
    const float4 biasO4 = *reinterpret_cast<const float4*>(bo_ + jv);
    float4 cst = *reinterpret_cast<const float4*>(c0 + (size_t)b * HID + jv);
    __syncthreads();    // drains gload_lds

    // ---- ALL W fragments -> registers: wf[part][kc][gate] (256 VGPR)
    const int bswz = (lrow & 7) << 4;
    bf16x8 wf[2][8][4];
    #pragma unroll
    for (int p = 0; p < 2; ++p) {
        #pragma unroll
        for (int kc = 0; kc < 8; ++kc) {
            int wbyte = (kc * 64 + hi * 16) ^ bswz;
            #pragma unroll
            for (int gg = 0; gg < 4; ++gg)
                wf[p][kc][gg] = *reinterpret_cast<const bf16x8*>(
                    smem + p * 32768 + gg * 8192 + lrow * 512 + wbyte);
        }
    }
    // LDS unused from here on.

    // ---- x pipeline: xpk = packed x(s); xt = in-flight x(s+1)
    float4 xt0[8], xt1[8];
    bf16x8 xpk[8];
    {
        const float* xr = x + (size_t)b * IND;
        #pragma unroll
        for (int kc = 0; kc < 8; ++kc) {
            const float* p = xr + kc * 32 + hi * 8;
            xt0[kc] = *reinterpret_cast<const float4*>(p);
            xt1[kc] = *reinterpret_cast<const float4*>(p + 4);
        }
        #pragma unroll
        for (int kc = 0; kc < 8; ++kc) xpk[kc] = pack8(xt0[kc], xt1[kc]);
        const float* xr1 = x + ((size_t)BATCH + b) * IND;
        #pragma unroll
        for (int kc = 0; kc < 8; ++kc) {
            const float* p = xr1 + kc * 32 + hi * 8;
            xt0[kc] = *reinterpret_cast<const float4*>(p);
            xt1[kc] = *reinterpret_cast<const float4*>(p + 4);
        }
    }

    unsigned char* regc[2] = {
        hr + (size_t)((0 * 16 + g_) * 16) * REG_BYTES,
        hr + (size_t)((1 * 16 + g_) * 16) * REG_BYTES };
    unsigned char* regp[2] = { regc[0] + J * REG_BYTES, regc[1] + J * REG_BYTES };
    const int uoff = lrow * 32 + (hi & 1) * 16;   // consumer in-region offset

    for (int s = 0; s < SEQ; ++s) {
        const u64 ee = (u64)(((unsigned)(s + 3) >> 1) & 1);
        const unsigned char* hsrc = regc[s & 1];

        // ---- issue initial h(s-1) probes (latency hides under phase A)
        u64 hq0[8], hq1[8];
        #pragma unroll
        for (int kc = 0; kc < 8; ++kc) {
            const u64* p = reinterpret_cast<const u64*>(
                hsrc + (2 * kc + (hi >> 1)) * REG_BYTES + uoff);
            hq0[kc] = __hip_atomic_load(p,     __ATOMIC_RELAXED, __HIP_MEMORY_SCOPE_AGENT);
            hq1[kc] = __hip_atomic_load(p + 1, __ATOMIC_RELAXED, __HIP_MEMORY_SCOPE_AGENT);
        }
        __builtin_amdgcn_sched_barrier(0);

        // ---- phase A: x-part MFMA, all operands in registers (swapped)
        f32x4 aF = {0.f, 0.f, 0.f, 0.f};
        f32x4 aI = {0.f, 0.f, 0.f, 0.f};
        f32x4 aG = {0.f, 0.f, 0.f, 0.f};
        f32x4 aO = {0.f, 0.f, 0.f, 0.f};
        #pragma unroll
        for (int kc = 0; kc < 8; ++kc) {
            aF = __builtin_amdgcn_mfma_f32_16x16x32_bf16(wf[0][kc][0], xpk[kc], aF, 0, 0, 0);
            aI = __builtin_amdgcn_mfma_f32_16x16x32_bf16(wf[0][kc][1], xpk[kc], aI, 0, 0, 0);
            aG = __builtin_amdgcn_mfma_f32_16x16x32_bf16(wf[0][kc][2], xpk[kc], aG, 0, 0, 0);
            aO = __builtin_amdgcn_mfma_f32_16x16x32_bf16(wf[0][kc][3], xpk[kc], aO, 0, 0, 0);
        }
        // pack x(s+1) (its loads landed a full step ago)
        #pragma unroll
        for (int kc = 0; kc < 8; ++kc) xpk[kc] = pack8(xt0[kc], xt1[kc]);
        __builtin_amdgcn_sched_barrier(0);

        // ---- wait kc 0-3 -> MFMA; then kc 4-7 -> MFMA (half-split arrival)
        #pragma unroll
        for (int half = 0; half < 2; ++half) {
            const int kb = half * 4;
            unsigned pend = 0;
            #pragma unroll
            for (int kc = 0; kc < 4; ++kc)
                if (!stamp_ok(hq0[kb + kc], hq1[kb + kc], ee)) pend |= (1u << kc);
            while (pend) {
                #pragma unroll
                for (int kc = 0; kc < 4; ++kc) {
                    if (pend & (1u << kc)) {
                        const u64* p = reinterpret_cast<const u64*>(
                            hsrc + (2 * (kb + kc) + (hi >> 1)) * REG_BYTES + uoff);
                        hq0[kb + kc] = __hip_atomic_load(p,     __ATOMIC_RELAXED, __HIP_MEMORY_SCOPE_AGENT);
                        hq1[kb + kc] = __hip_atomic_load(p + 1, __ATOMIC_RELAXED, __HIP_MEMORY_SCOPE_AGENT);
                        if (stamp_ok(hq0[kb + kc], hq1[kb + kc], ee)) pend &= ~(1u << kc);
                    }
                }
            }
            #pragma unroll
            for (int kc = 0; kc < 4; ++kc) {
                union { u64 q[2]; bf16x8 v; } u;
                u.q[0] = hq0[kb + kc]; u.q[1] = hq1[kb + kc];
                aF = __builtin_amdgcn_mfma_f32_16x16x32_bf16(wf[1][kb + kc][0], u.v, aF, 0, 0, 0);
                aI = __builtin_amdgcn_mfma_f32_16x16x32_bf16(wf[1][kb + kc][1], u.v, aI, 0, 0, 0);
                aG = __builtin_amdgcn_mfma_f32_16x16x32_bf16(wf[1][kb + kc][2], u.v, aG, 0, 0, 0);
                aO = __builtin_amdgcn_mfma_f32_16x16x32_bf16(wf[1][kb + kc][3], u.v, aO, 0, 0, 0);
            }
        }

        // ---- epilogue: 4 consecutive j at this lane's b — register-local
        float hv[4];
        #pragma unroll
        for (int r = 0; r < 4; ++r) {
            float fg = sigmoid_f(aF[r] + ((const float*)&biasF4)[r]);
            float ig = sigmoid_f(aI[r] + ((const float*)&biasI4)[r]);
            float gg = tanh_f(aG[r] + ((const float*)&biasG4)[r]);
            float og = sigmoid_f(aO[r] + ((const float*)&biasO4)[r]);
            ((float*)&cst)[r] = fg * ((const float*)&cst)[r] + ig * gg;
            hv[r] = og * tanh_f(((const float*)&cst)[r]);
        }

        // ---- stamped 8B ring word straight from registers (chain-critical)
        {
            u64 wv = (u64)(unsigned short)f2bf(hv[0])
                   | ((u64)(unsigned short)f2bf(hv[1]) << 16)
                   | ((u64)(unsigned short)f2bf(hv[2]) << 32)
                   | ((u64)(unsigned short)f2bf(hv[3]) << 48);
            wv = (wv & ~1ULL) | (u64)((s >> 1) & 1);
            __hip_atomic_store(
                reinterpret_cast<u64*>(regp[(s + 1) & 1] + lrow * 32 + hi * 8),
                wv, __ATOMIC_RELAXED, __HIP_MEMORY_SCOPE_AGENT);
        }
        // ---- off-chain: out store, x(s+2) prefetch, final states
        {
            float4 ov = { hv[0], hv[1], hv[2], hv[3] };
            *reinterpret_cast<float4*>(
                out + (size_t)s * (BATCH * HID) + (size_t)b * HID + jv) = ov;
        }
        if (s + 2 < SEQ) {
            const float* xr = x + ((size_t)(s + 2) * BATCH + b) * IND;
            #pragma unroll
            for (int kc = 0; kc < 8; ++kc) {
                const float* p = xr + kc * 32 + hi * 8;
                xt0[kc] = *reinterpret_cast<const float4*>(p);
                xt1[kc] = *reinterpret_cast<const float4*>(p + 4);
            }
        }
        if (s == SEQ - 1) {
            *reinterpret_cast<float4*>(hx  + (size_t)b * HID + jv) =
                (float4){ hv[0], hv[1], hv[2], hv[3] };
            *reinterpret_cast<float4*>(cxg + (size_t)b * HID + jv) = cst;
        }
    }
}

extern "C" void kernel_launch(void* const* d_in, const int* in_sizes, int n_in,
                              void* d_out, int out_size, void* d_ws, size_t ws_size,
                              hipStream_t stream) {
    const float* x  = (const float*)d_in[0];
    const float* h0 = (const float*)d_in[1];
    const float* c0 = (const float*)d_in[2];
    const float* Wf = (const float*)d_in[3];
    const float* bf = (const float*)d_in[4];
    const float* Wi = (const float*)d_in[5];
    const float* bi = (const float*)d_in[6];
    const float* Wg = (const float*)d_in[7];
    const float* bg = (const float*)d_in[8];
    const float* Wo = (const float*)d_in[9];
    const float* bo = (const float*)d_in[10];

    float* out = (float*)d_out;
    float* hx  = out + (size_t)SEQ * BATCH * HID;
    float* cx  = hx + BATCH * HID;

    unsigned char* wb = (unsigned char*)d_ws;
    unsigned char* hr = wb + WB_BYTES;

    prep_w<<<256, 256, 0, stream>>>(Wf, Wi, Wg, Wo, wb);
    prep_h0<<<128, 256, 0, stream>>>(h0, hr);
    lstm_seq<<<256, 64, 65536, stream>>>(x, c0, bf, bi, bg, bo,
                                         wb, hr, out, hx, cx);
}

// Round 14
// 2162.250 us; speedup vs baseline: 1.6989x; 1.2586x over previous
//
#include <hip/hip_runtime.h>
#include <hip/hip_bf16.h>
#include <math.h>

#define SEQ   1024
#define BATCH 256
#define IND   256
#define HID   256
#define NGATE 4

// ws layout:
//   wb : bf16 [2 parts][4 gates][256 j][256 k], swizzled rows (1 MiB) @ 0
//   hr : ring [2 slots][16 g][16 J] regions of 512B: word(b,j4) = 4 bf16
//        {h[b][16J+j4..+3]}, elem-0 LSB = step stamp; single writer @ 1 MiB
#define WB_BYTES   (2 * NGATE * HID * 256 * 2)
#define REG_BYTES  512

typedef float  f32x4  __attribute__((ext_vector_type(4)));
typedef short  bf16x8 __attribute__((ext_vector_type(8)));
typedef unsigned long long u64;

__device__ __forceinline__ short f2bf(float x) {
    __hip_bfloat16 h = __float2bfloat16(x);
    return *reinterpret_cast<short*>(&h);
}

__device__ __forceinline__ bf16x8 pack8(const float4& a, const float4& b) {
    union { short sh[8]; bf16x8 v; } u;
    u.sh[0] = f2bf(a.x); u.sh[1] = f2bf(a.y); u.sh[2] = f2bf(a.z); u.sh[3] = f2bf(a.w);
    u.sh[4] = f2bf(b.x); u.sh[5] = f2bf(b.y); u.sh[6] = f2bf(b.z); u.sh[7] = f2bf(b.w);
    return u.v;
}

__device__ __forceinline__ void gload_lds16(const void* g, void* l) {
    __builtin_amdgcn_global_load_lds(
        (const __attribute__((address_space(1))) unsigned int*)g,
        (__attribute__((address_space(3))) unsigned int*)l, 16, 0, 0);
}

__device__ __forceinline__ float sigmoid_f(float z) {
    return 1.f / (1.f + __expf(-z));
}
__device__ __forceinline__ float tanh_f(float v) {
    return 2.f / (1.f + __expf(-2.f * v)) - 1.f;
}

__device__ __forceinline__ bool stamp_ok(u64 q0, u64 q1, u64 ee) {
    return ((((q0 ^ ee) | (q1 ^ ee)) & 1ULL) == 0ULL);
}

// ---------------- prep kernels (identical to R9/R13) ----------------

__global__ __launch_bounds__(256) void prep_w(
    const float* __restrict__ Wf, const float* __restrict__ Wi,
    const float* __restrict__ Wg, const float* __restrict__ Wo,
    unsigned char* __restrict__ wb)
{
    int chunk = blockIdx.x * 256 + threadIdx.x;   // 65536 chunks of 8 floats
    int g  = chunk >> 14;
    int jj = (chunk >> 6) & 255;
    int k0 = (chunk & 63) * 8;
    int p  = k0 >> 8;
    int kk = k0 & 255;
    const float* W = (g == 0) ? Wf : (g == 1) ? Wi : (g == 2) ? Wg : Wo;
    const float* src = W + (size_t)jj * 512 + k0;
    float4 a = *reinterpret_cast<const float4*>(src);
    float4 b = *reinterpret_cast<const float4*>(src + 4);
    size_t dstrow = (size_t)((p * 4 + g) * 256 + jj);
    *reinterpret_cast<bf16x8*>(
        wb + dstrow * 512 + ((kk * 2) ^ ((jj & 7) << 4))) = pack8(a, b);
}

__global__ __launch_bounds__(256) void prep_h0(
    const float* __restrict__ h0, unsigned char* __restrict__ hr)
{
    int idx  = blockIdx.x * 256 + threadIdx.x;    // 32768 chunks of 8 B
    int slot = idx >> 14;
    int g    = (idx >> 10) & 15;
    int J    = (idx >> 6) & 15;
    int c    = idx & 63;
    int br   = c >> 2;
    int j4   = (c & 3) * 4;
    const float* src = h0 + (size_t)(g * 16 + br) * HID + J * 16 + j4;
    unsigned short v[4];
    #pragma unroll
    for (int i = 0; i < 4; ++i)
        v[i] = (unsigned short)((unsigned short)f2bf(src[i]) | 1u);
    u64 q = (u64)v[0] | ((u64)v[1] << 16) | ((u64)v[2] << 32) | ((u64)v[3] << 48);
    *reinterpret_cast<u64*>(
        hr + (size_t)((slot * 16 + g) * 16 + J) * REG_BYTES + c * 8) = q;
}

// ---------------- persistent sequence kernel ----------------
// 256 blocks x 64 threads. g_ = blk&15 (XCD-local peers, heuristic),
// J = blk>>4. Operand-swapped MFMA (acc col=b, row=j): each lane owns
// (b = b0+lrow, j = j0+hi*4 .. +3) -> stamped 8B ring word packed straight
// from registers. BOTH W parts in registers; LDS only for one-time staging.
// vmcnt discipline: x(s+2) is issued in the ONLY window where it pollutes no
// probe read — after the last probe consumption of step s, before the
// epilogue. Probe loop = half-split arrival (kc 0-3 while 4-7 settle).
__global__ __launch_bounds__(64, 1) void lstm_seq(
    const float* __restrict__ x,  const float* __restrict__ c0,
    const float* __restrict__ bf_, const float* __restrict__ bi_,
    const float* __restrict__ bg_, const float* __restrict__ bo_,
    const unsigned char* __restrict__ wb, unsigned char* __restrict__ hr,
    float* __restrict__ out, float* __restrict__ hx, float* __restrict__ cxg)
{
    extern __shared__ __align__(16) unsigned char smem[];   // 64 KiB, init only

    const int lane = threadIdx.x & 63;
    const int blk  = blockIdx.x;
    const int g_   = blk & 15;
    const int J    = blk >> 4;
    const int j0   = J * 16;
    const int b0   = g_ * 16;

    const int lrow = lane & 15;
    const int hi   = lane >> 4;
    const int b    = b0 + lrow;          // this lane's batch row (acc col)
    const int jv   = j0 + hi * 4;        // this lane's first j (acc row base)

    // ---- stage W tile (64 KiB) into LDS once
    #pragma unroll
    for (int i = 0; i < 64; ++i) {
        gload_lds16(wb + ((size_t)((i >> 3) * 256 + j0 + (i & 7) * 2)) * 512
                       + lane * 16,
                    smem + i * 1024);
    }
    const float4 biasF4 = *reinterpret_cast<const float4*>(bf_ + jv);
    const float4 biasI4 = *reinterpret_cast<const float4*>(bi_ + jv);
    const float4 biasG4 = *reinterpret_cast<const float4*>(bg_ + jv);
    const float4 biasO4 = *reinterpret_cast<const float4*>(bo_ + jv);
    float4 cst = *reinterpret_cast<const float4*>(c0 + (size_t)b * HID + jv);
    __syncthreads();    // drains gload_lds

    // ---- ALL W fragments -> registers: wf[part][kc][gate] (256 VGPR)
    const int bswz = (lrow & 7) << 4;
    bf16x8 wf[2][8][4];
    #pragma unroll
    for (int p = 0; p < 2; ++p) {
        #pragma unroll
        for (int kc = 0; kc < 8; ++kc) {
            int wbyte = (kc * 64 + hi * 16) ^ bswz;
            #pragma unroll
            for (int gg = 0; gg < 4; ++gg)
                wf[p][kc][gg] = *reinterpret_cast<const bf16x8*>(
                    smem + p * 32768 + gg * 8192 + lrow * 512 + wbyte);
        }
    }
    // LDS unused from here on.

    // ---- x pipeline: xpk = packed x(s); xt = in-flight x(s+1)
    float4 xt0[8], xt1[8];
    bf16x8 xpk[8];
    {
        const float* xr = x + (size_t)b * IND;
        #pragma unroll
        for (int kc = 0; kc < 8; ++kc) {
            const float* p = xr + kc * 32 + hi * 8;
            xt0[kc] = *reinterpret_cast<const float4*>(p);
            xt1[kc] = *reinterpret_cast<const float4*>(p + 4);
        }
        #pragma unroll
        for (int kc = 0; kc < 8; ++kc) xpk[kc] = pack8(xt0[kc], xt1[kc]);
        const float* xr1 = x + ((size_t)BATCH + b) * IND;
        #pragma unroll
        for (int kc = 0; kc < 8; ++kc) {
            const float* p = xr1 + kc * 32 + hi * 8;
            xt0[kc] = *reinterpret_cast<const float4*>(p);
            xt1[kc] = *reinterpret_cast<const float4*>(p + 4);
        }
    }

    unsigned char* regc[2] = {
        hr + (size_t)((0 * 16 + g_) * 16) * REG_BYTES,
        hr + (size_t)((1 * 16 + g_) * 16) * REG_BYTES };
    unsigned char* regp[2] = { regc[0] + J * REG_BYTES, regc[1] + J * REG_BYTES };
    const int uoff = lrow * 32 + (hi & 1) * 16;   // consumer in-region offset

    for (int s = 0; s < SEQ; ++s) {
        const u64 ee = (u64)(((unsigned)(s + 3) >> 1) & 1);
        const unsigned char* hsrc = regc[s & 1];

        // ---- issue initial h(s-1) probes (latency hides under phase A;
        //      no older VMEM ops outstanding except acked stores)
        u64 hq0[8], hq1[8];
        #pragma unroll
        for (int kc = 0; kc < 8; ++kc) {
            const u64* p = reinterpret_cast<const u64*>(
                hsrc + (2 * kc + (hi >> 1)) * REG_BYTES + uoff);
            hq0[kc] = __hip_atomic_load(p,     __ATOMIC_RELAXED, __HIP_MEMORY_SCOPE_AGENT);
            hq1[kc] = __hip_atomic_load(p + 1, __ATOMIC_RELAXED, __HIP_MEMORY_SCOPE_AGENT);
        }
        __builtin_amdgcn_sched_barrier(0);

        // ---- phase A: x-part MFMA, all operands in registers (swapped)
        f32x4 aF = {0.f, 0.f, 0.f, 0.f};
        f32x4 aI = {0.f, 0.f, 0.f, 0.f};
        f32x4 aG = {0.f, 0.f, 0.f, 0.f};
        f32x4 aO = {0.f, 0.f, 0.f, 0.f};
        #pragma unroll
        for (int kc = 0; kc < 8; ++kc) {
            aF = __builtin_amdgcn_mfma_f32_16x16x32_bf16(wf[0][kc][0], xpk[kc], aF, 0, 0, 0);
            aI = __builtin_amdgcn_mfma_f32_16x16x32_bf16(wf[0][kc][1], xpk[kc], aI, 0, 0, 0);
            aG = __builtin_amdgcn_mfma_f32_16x16x32_bf16(wf[0][kc][2], xpk[kc], aG, 0, 0, 0);
            aO = __builtin_amdgcn_mfma_f32_16x16x32_bf16(wf[0][kc][3], xpk[kc], aO, 0, 0, 0);
        }
        // pack x(s+1) (its loads landed a full step ago)
        #pragma unroll
        for (int kc = 0; kc < 8; ++kc) xpk[kc] = pack8(xt0[kc], xt1[kc]);
        __builtin_amdgcn_sched_barrier(0);

        // ---- wait kc 0-3 -> MFMA; then kc 4-7 -> MFMA (half-split arrival).
        //      No younger VMEM ops are issued anywhere in this region, so
        //      every probe's counted waitcnt waits ONLY on probes.
        #pragma unroll
        for (int half = 0; half < 2; ++half) {
            const int kb = half * 4;
            unsigned pend = 0;
            #pragma unroll
            for (int kc = 0; kc < 4; ++kc)
                if (!stamp_ok(hq0[kb + kc], hq1[kb + kc], ee)) pend |= (1u << kc);
            while (pend) {
                #pragma unroll
                for (int kc = 0; kc < 4; ++kc) {
                    if (pend & (1u << kc)) {
                        const u64* p = reinterpret_cast<const u64*>(
                            hsrc + (2 * (kb + kc) + (hi >> 1)) * REG_BYTES + uoff);
                        hq0[kb + kc] = __hip_atomic_load(p,     __ATOMIC_RELAXED, __HIP_MEMORY_SCOPE_AGENT);
                        hq1[kb + kc] = __hip_atomic_load(p + 1, __ATOMIC_RELAXED, __HIP_MEMORY_SCOPE_AGENT);
                        if (stamp_ok(hq0[kb + kc], hq1[kb + kc], ee)) pend &= ~(1u << kc);
                    }
                }
            }
            #pragma unroll
            for (int kc = 0; kc < 4; ++kc) {
                union { u64 q[2]; bf16x8 v; } u;
                u.q[0] = hq0[kb + kc]; u.q[1] = hq1[kb + kc];
                aF = __builtin_amdgcn_mfma_f32_16x16x32_bf16(wf[1][kb + kc][0], u.v, aF, 0, 0, 0);
                aI = __builtin_amdgcn_mfma_f32_16x16x32_bf16(wf[1][kb + kc][1], u.v, aI, 0, 0, 0);
                aG = __builtin_amdgcn_mfma_f32_16x16x32_bf16(wf[1][kb + kc][2], u.v, aG, 0, 0, 0);
                aO = __builtin_amdgcn_mfma_f32_16x16x32_bf16(wf[1][kb + kc][3], u.v, aO, 0, 0, 0);
            }
        }
        __builtin_amdgcn_sched_barrier(0);

        // ---- x(s+2) prefetch — THE window: younger than every probe read of
        //      step s, and separated from step s+1's probe reads by
        //      phase B tail + epilogue + stores + next phase A (~800 cy).
        if (s + 2 < SEQ) {
            const float* xr = x + ((size_t)(s + 2) * BATCH + b) * IND;
            #pragma unroll
            for (int kc = 0; kc < 8; ++kc) {
                const float* p = xr + kc * 32 + hi * 8;
                xt0[kc] = *reinterpret_cast<const float4*>(p);
                xt1[kc] = *reinterpret_cast<const float4*>(p + 4);
            }
        }
        __builtin_amdgcn_sched_barrier(0);

        // ---- epilogue: 4 consecutive j at this lane's b — register-local
        float hv[4];
        #pragma unroll
        for (int r = 0; r < 4; ++r) {
            float fg = sigmoid_f(aF[r] + ((const float*)&biasF4)[r]);
            float ig = sigmoid_f(aI[r] + ((const float*)&biasI4)[r]);
            float gg = tanh_f(aG[r] + ((const float*)&biasG4)[r]);
            float og = sigmoid_f(aO[r] + ((const float*)&biasO4)[r]);
            ((float*)&cst)[r] = fg * ((const float*)&cst)[r] + ig * gg;
            hv[r] = og * tanh_f(((const float*)&cst)[r]);
        }

        // ---- stamped 8B ring word straight from registers (chain-critical)
        {
            u64 wv = (u64)(unsigned short)f2bf(hv[0])
                   | ((u64)(unsigned short)f2bf(hv[1]) << 16)
                   | ((u64)(unsigned short)f2bf(hv[2]) << 32)
                   | ((u64)(unsigned short)f2bf(hv[3]) << 48);
            wv = (wv & ~1ULL) | (u64)((s >> 1) & 1);
            __hip_atomic_store(
                reinterpret_cast<u64*>(regp[(s + 1) & 1] + lrow * 32 + hi * 8),
                wv, __ATOMIC_RELAXED, __HIP_MEMORY_SCOPE_AGENT);
        }
        // ---- off-chain: out store, final states
        {
            float4 ov = { hv[0], hv[1], hv[2], hv[3] };
            *reinterpret_cast<float4*>(
                out + (size_t)s * (BATCH * HID) + (size_t)b * HID + jv) = ov;
        }
        if (s == SEQ - 1) {
            *reinterpret_cast<float4*>(hx  + (size_t)b * HID + jv) =
                (float4){ hv[0], hv[1], hv[2], hv[3] };
            *reinterpret_cast<float4*>(cxg + (size_t)b * HID + jv) = cst;
        }
    }
}

extern "C" void kernel_launch(void* const* d_in, const int* in_sizes, int n_in,
                              void* d_out, int out_size, void* d_ws, size_t ws_size,
                              hipStream_t stream) {
    const float* x  = (const float*)d_in[0];
    const float* h0 = (const float*)d_in[1];
    const float* c0 = (const float*)d_in[2];
    const float* Wf = (const float*)d_in[3];
    const float* bf = (const float*)d_in[4];
    const float* Wi = (const float*)d_in[5];
    const float* bi = (const float*)d_in[6];
    const float* Wg = (const float*)d_in[7];
    const float* bg = (const float*)d_in[8];
    const float* Wo = (const float*)d_in[9];
    const float* bo = (const float*)d_in[10];

    float* out = (float*)d_out;
    float* hx  = out + (size_t)SEQ * BATCH * HID;
    float* cx  = hx + BATCH * HID;

    unsigned char* wb = (unsigned char*)d_ws;
    unsigned char* hr = wb + WB_BYTES;

    prep_w<<<256, 256, 0, stream>>>(Wf, Wi, Wg, Wo, wb);
    prep_h0<<<128, 256, 0, stream>>>(h0, hr);
    lstm_seq<<<256, 64, 65536, stream>>>(x, c0, bf, bi, bg, bo,
                                         wb, hr, out, hx, cx);
}